// Round 3
// baseline (965.136 us; speedup 1.0000x reference)
//
#include <hip/hip_runtime.h>

#define B_ 8
#define T_ 12
#define P_ 1000
#define N_ 20000
#define E_ 60000
#define FP_ 32
#define FN_ 32
#define HO_ 12
#define IND 768
#define M_ (B_*N_)   // 160000 rows

typedef __attribute__((ext_vector_type(8))) short bf16x8;
typedef __attribute__((ext_vector_type(4))) float f32x4;

__device__ __forceinline__ unsigned short f2bf(float x) {
    union { float f; unsigned int u; } v; v.f = x;
    unsigned int u = v.u;
    u += 0x7fffu + ((u >> 16) & 1u);   // RNE
    return (unsigned short)(u >> 16);
}

#define GLDS16(gp, lp) \
    __builtin_amdgcn_global_load_lds((const __attribute__((address_space(1))) void*)(gp), \
                                     (__attribute__((address_space(3))) void*)(lp), 16, 0, 0)

// ---------------- CSR build ----------------
__global__ void k_count(const int* __restrict__ mapper, int* __restrict__ counts) {
    int e = blockIdx.x * 256 + threadIdx.x;
    if (e < E_) atomicAdd(&counts[mapper[e]], 1);
}

__global__ __launch_bounds__(1024) void k_scan(const int* __restrict__ counts,
                                               int* __restrict__ offsets,
                                               int* __restrict__ cursor) {
    __shared__ int ps[1024];
    const int tid = threadIdx.x;
    const int CH = 20;                       // 1024*20 = 20480 >= N_
    const int base = tid * CH;
    int s = 0;
    for (int i = 0; i < CH; ++i) { int idx = base + i; if (idx < N_) s += counts[idx]; }
    ps[tid] = s;
    __syncthreads();
    for (int off = 1; off < 1024; off <<= 1) {
        int v = ps[tid];
        int a = (tid >= off) ? ps[tid - off] : 0;
        __syncthreads();
        ps[tid] = v + a;
        __syncthreads();
    }
    int run = (tid > 0) ? ps[tid - 1] : 0;   // exclusive base
    for (int i = 0; i < CH; ++i) {
        int idx = base + i;
        if (idx < N_) { offsets[idx] = run; cursor[idx] = run; run += counts[idx]; }
    }
    if (tid == 1023) offsets[N_] = ps[1023];
}

__global__ void k_scatter(const int* __restrict__ mapper, const int* __restrict__ batch,
                          int* __restrict__ cursor, int* __restrict__ edge_p) {
    int e = blockIdx.x * 256 + threadIdx.x;
    if (e < E_) {
        int pos = atomicAdd(&cursor[mapper[e]], 1);
        edge_p[pos] = batch[e];
    }
}

// ---------------- weight prep: W1t[h][d]=bf16(W1[d][h]); W2t[o<16][k]=bf16(W2[k][o]) ----------------
__global__ void k_wprep(const float* __restrict__ W1, const float* __restrict__ W2,
                        unsigned short* __restrict__ W1t, unsigned short* __restrict__ W2t) {
    int i = blockIdx.x * 256 + threadIdx.x;
    if (i < IND * IND) {
        int h = i / IND, d = i - h * IND;
        W1t[i] = f2bf(W1[d * IND + h]);
    } else {
        int j = i - IND * IND;
        if (j < 16 * IND) {
            int o = j / IND, k = j - o * IND;
            W2t[j] = (o < HO_) ? f2bf(W2[k * HO_ + o]) : (unsigned short)0;
        }
    }
}

// ---------------- stage mlp_in (bf16): row r=b*N+n, cols [0,384)=nodes_x^T, [384,768)=patch-mean ----------------
__global__ __launch_bounds__(256) void k_stage(const float* __restrict__ patch_x,
                                               const float* __restrict__ nodes_x,
                                               const int* __restrict__ offsets,
                                               const int* __restrict__ edge_p,
                                               unsigned short* __restrict__ X) {
    const int gw = (blockIdx.x * 256 + threadIdx.x) >> 6;   // one wave per row
    const int lane = threadIdx.x & 63;
    const int b = gw / N_;
    const int n = gw - b * N_;
    unsigned short* xr = X + (size_t)gw * IND;
    #pragma unroll
    for (int j = 0; j < 6; ++j) {
        const int c = lane + j * 64;
        const int tt = c >> 5, f = c & 31;
        xr[c] = f2bf(nodes_x[((b * T_ + tt) * N_ + n) * FN_ + f]);
    }
    const int s = offsets[n], e = offsets[n + 1];
    const float inv = (e > s) ? 1.0f / (float)(e - s) : 0.0f;
    #pragma unroll
    for (int j = 0; j < 6; ++j) {
        const int c = lane + j * 64;
        const int tt = c >> 5, f = c & 31;
        float a = 0.f;
        for (int q = s; q < e; ++q) {
            const int p = edge_p[q];
            a += patch_x[((b * T_ + tt) * P_ + p) * FP_ + f];
        }
        xr[384 + c] = f2bf(a * inv);
    }
}

// ---------------- GEMM1: H = relu(X @ W1 + b1), bf16 out. 128x128 tile, BK=64, 4 waves 2x2 ----------------
__global__ __launch_bounds__(256, 2) void k_gemm1(const unsigned short* __restrict__ X,
                                                  const unsigned short* __restrict__ W1t,
                                                  const float* __restrict__ b1,
                                                  unsigned short* __restrict__ Hbuf) {
    __shared__ __align__(16) unsigned short As[128 * 64];
    __shared__ __align__(16) unsigned short Bs[128 * 64];
    const int t = threadIdx.x;
    const int lane = t & 63;
    const int w = t >> 6;
    const int wr = w >> 1, wc = w & 1;
    const int col0 = blockIdx.x * 128;   // 6 col tiles (x fastest -> 6 blocks share A tile)
    const int row0 = blockIdx.y * 128;   // 1250 row tiles
    const int l15 = lane & 15;
    const int lhi = lane >> 4;

    f32x4 acc[4][4] = {};

    for (int kt = 0; kt < 12; ++kt) {
        const int k0 = kt * 64;
        #pragma unroll
        for (int i = 0; i < 4; ++i) {
            const int f = i * 2048 + t * 8;
            GLDS16(X + (row0 + (f >> 6)) * IND + k0 + (f & 63), &As[f]);
        }
        #pragma unroll
        for (int i = 0; i < 4; ++i) {
            const int f = i * 2048 + t * 8;
            GLDS16(W1t + (col0 + (f >> 6)) * IND + k0 + (f & 63), &Bs[f]);
        }
        __syncthreads();
        #pragma unroll
        for (int kk = 0; kk < 2; ++kk) {
            const int ko = kk * 32 + lhi * 8;
            bf16x8 af[4], bfr[4];
            #pragma unroll
            for (int m = 0; m < 4; ++m)
                af[m] = *(const bf16x8*)&As[(wr * 64 + m * 16 + l15) * 64 + ko];
            #pragma unroll
            for (int n = 0; n < 4; ++n)
                bfr[n] = *(const bf16x8*)&Bs[(wc * 64 + n * 16 + l15) * 64 + ko];
            #pragma unroll
            for (int m = 0; m < 4; ++m)
                #pragma unroll
                for (int n = 0; n < 4; ++n)
                    acc[m][n] = __builtin_amdgcn_mfma_f32_16x16x32_bf16(af[m], bfr[n], acc[m][n], 0, 0, 0);
        }
        __syncthreads();
    }
    // epilogue: bias + relu + bf16 store. C/D map: col=lane&15, row=(lane>>4)*4+r
    #pragma unroll
    for (int n = 0; n < 4; ++n) {
        const int col = col0 + wc * 64 + n * 16 + l15;
        const float bb = b1[col];
        #pragma unroll
        for (int m = 0; m < 4; ++m) {
            #pragma unroll
            for (int r = 0; r < 4; ++r) {
                const int row = row0 + wr * 64 + m * 16 + lhi * 4 + r;
                float v = acc[m][n][r] + bb;
                v = v > 0.f ? v : 0.f;
                Hbuf[(size_t)row * IND + col] = f2bf(v);
            }
        }
    }
}

// ---------------- GEMM2: out = H @ W2 + b2. One 16x16 MFMA tile per wave (cols 12..15 padded 0) ----------------
__global__ __launch_bounds__(256) void k_gemm2(const unsigned short* __restrict__ Hbuf,
                                               const unsigned short* __restrict__ W2t,
                                               const float* __restrict__ b2,
                                               float* __restrict__ out) {
    const int t = threadIdx.x;
    const int lane = t & 63;
    const int w = t >> 6;
    const int tile = blockIdx.x * 4 + w;    // 10000 tiles of 16 rows
    const int row0 = tile * 16;
    const int l15 = lane & 15, lhi = lane >> 4;
    f32x4 acc = {};
    const unsigned short* hrow = Hbuf + (size_t)(row0 + l15) * IND;
    const unsigned short* wrow = W2t + l15 * IND;
    #pragma unroll 8
    for (int kk = 0; kk < 24; ++kk) {
        const int ko = kk * 32 + lhi * 8;
        bf16x8 a = *(const bf16x8*)&hrow[ko];
        bf16x8 b = *(const bf16x8*)&wrow[ko];
        acc = __builtin_amdgcn_mfma_f32_16x16x32_bf16(a, b, acc, 0, 0, 0);
    }
    if (l15 < HO_) {
        const float bb = b2[l15];
        #pragma unroll
        for (int r = 0; r < 4; ++r) {
            const int row = row0 + lhi * 4 + r;
            out[row * HO_ + l15] = acc[r] + bb;
        }
    }
}

extern "C" void kernel_launch(void* const* d_in, const int* in_sizes, int n_in,
                              void* d_out, int out_size, void* d_ws, size_t ws_size,
                              hipStream_t stream) {
    const float* patch_x = (const float*)d_in[0];
    const float* nodes_x = (const float*)d_in[1];
    const int*   sb      = (const int*)d_in[2];
    const int*   snm     = (const int*)d_in[3];
    const float* W1      = (const float*)d_in[4];
    const float* b1      = (const float*)d_in[5];
    const float* W2      = (const float*)d_in[6];
    const float* b2      = (const float*)d_in[7];
    float* out = (float*)d_out;

    char* ws = (char*)d_ws;
    size_t off = 0;
    auto alloc = [&](size_t bytes) -> void* {
        void* p = ws + off;
        off = (off + bytes + 255) & ~(size_t)255;
        return p;
    };
    int* counts  = (int*)alloc((size_t)N_ * 4);
    int* offsets = (int*)alloc((size_t)(N_ + 1) * 4);
    int* cursor  = (int*)alloc((size_t)N_ * 4);
    int* edge_p  = (int*)alloc((size_t)E_ * 4);
    unsigned short* W1t = (unsigned short*)alloc((size_t)IND * IND * 2);
    unsigned short* W2t = (unsigned short*)alloc((size_t)16 * IND * 2);
    unsigned short* X   = (unsigned short*)alloc((size_t)M_ * IND * 2);
    unsigned short* Hb  = (unsigned short*)alloc((size_t)M_ * IND * 2);

    hipMemsetAsync(counts, 0, (size_t)N_ * 4, stream);
    k_count  <<<(E_ + 255) / 256, 256, 0, stream>>>(snm, counts);
    k_scan   <<<1, 1024, 0, stream>>>(counts, offsets, cursor);
    k_scatter<<<(E_ + 255) / 256, 256, 0, stream>>>(snm, sb, cursor, edge_p);
    k_wprep  <<<(IND * IND + 16 * IND) / 256, 256, 0, stream>>>(W1, W2, W1t, W2t);
    k_stage  <<<M_ / 4, 256, 0, stream>>>(patch_x, nodes_x, offsets, edge_p, X);
    k_gemm1  <<<dim3(6, 1250), 256, 0, stream>>>(X, W1t, b1, Hb);
    k_gemm2  <<<2500, 256, 0, stream>>>(Hb, W2t, b2, out);
}

// Round 5
// 722.606 us; speedup vs baseline: 1.3356x; 1.3356x over previous
//
#include <hip/hip_runtime.h>

#define B_ 8
#define T_ 12
#define P_ 1000
#define N_ 20000
#define E_ 60000
#define FP_ 32
#define FN_ 32
#define HO_ 12
#define IND 768
#define M_ (B_*N_)   // 160000 rows

typedef __attribute__((ext_vector_type(8))) short bf16x8;
typedef __attribute__((ext_vector_type(4))) float f32x4;

__device__ __forceinline__ unsigned short f2bf(float x) {
    union { float f; unsigned int u; } v; v.f = x;
    unsigned int u = v.u;
    u += 0x7fffu + ((u >> 16) & 1u);   // RNE
    return (unsigned short)(u >> 16);
}

#define GLDS16(gp, lp) \
    __builtin_amdgcn_global_load_lds((const __attribute__((address_space(1))) void*)(gp), \
                                     (__attribute__((address_space(3))) void*)(lp), 16, 0, 0)

// ---------------- CSR build ----------------
__global__ void k_count(const int* __restrict__ mapper, int* __restrict__ counts) {
    int e = blockIdx.x * 256 + threadIdx.x;
    if (e < E_) atomicAdd(&counts[mapper[e]], 1);
}

__global__ __launch_bounds__(1024) void k_scan(const int* __restrict__ counts,
                                               int* __restrict__ offsets,
                                               int* __restrict__ cursor) {
    __shared__ int ps[1024];
    const int tid = threadIdx.x;
    const int CH = 20;                       // 1024*20 = 20480 >= N_
    const int base = tid * CH;
    int s = 0;
    for (int i = 0; i < CH; ++i) { int idx = base + i; if (idx < N_) s += counts[idx]; }
    ps[tid] = s;
    __syncthreads();
    for (int off = 1; off < 1024; off <<= 1) {
        int v = ps[tid];
        int a = (tid >= off) ? ps[tid - off] : 0;
        __syncthreads();
        ps[tid] = v + a;
        __syncthreads();
    }
    int run = (tid > 0) ? ps[tid - 1] : 0;   // exclusive base
    for (int i = 0; i < CH; ++i) {
        int idx = base + i;
        if (idx < N_) { offsets[idx] = run; cursor[idx] = run; run += counts[idx]; }
    }
    if (tid == 1023) offsets[N_] = ps[1023];
}

__global__ void k_scatter(const int* __restrict__ mapper, const int* __restrict__ batch,
                          int* __restrict__ cursor, int* __restrict__ edge_p) {
    int e = blockIdx.x * 256 + threadIdx.x;
    if (e < E_) {
        int pos = atomicAdd(&cursor[mapper[e]], 1);
        edge_p[pos] = batch[e];
    }
}

// ---------------- weight prep: W1t[h][d]=bf16(W1[d][h]); W2t[o<16][k]=bf16(W2[k][o]) ----------------
__global__ void k_wprep(const float* __restrict__ W1, const float* __restrict__ W2,
                        unsigned short* __restrict__ W1t, unsigned short* __restrict__ W2t) {
    int i = blockIdx.x * 256 + threadIdx.x;
    if (i < IND * IND) {
        int h = i / IND, d = i - h * IND;
        W1t[i] = f2bf(W1[d * IND + h]);
    } else {
        int j = i - IND * IND;
        if (j < 16 * IND) {
            int o = j / IND, k = j - o * IND;
            W2t[j] = (o < HO_) ? f2bf(W2[k * HO_ + o]) : (unsigned short)0;
        }
    }
}

// ---------------- stage mlp_in (bf16): row r=b*N+n, cols [0,384)=nodes_x^T, [384,768)=patch-mean ----------------
// v2: edge list hoisted to registers (shfl broadcast), float2 loads, packed 2xbf16 stores.
__global__ __launch_bounds__(256) void k_stage(const float* __restrict__ patch_x,
                                               const float* __restrict__ nodes_x,
                                               const int* __restrict__ offsets,
                                               const int* __restrict__ edge_p,
                                               unsigned short* __restrict__ X) {
    const int gw = (blockIdx.x * 256 + threadIdx.x) >> 6;   // one wave per row
    const int lane = threadIdx.x & 63;
    const int b = gw / N_;
    const int n = gw - b * N_;
    unsigned short* xr = X + (size_t)gw * IND;

    int tt[3], ff[3];
    #pragma unroll
    for (int j = 0; j < 3; ++j) {
        const int c = 2 * (j * 64 + lane);     // even col in [0,384)
        tt[j] = c >> 5; ff[j] = c & 31;        // pair (f, f+1) stays within one t
    }

    // nodes part: cols [0,384)
    const float* nb = nodes_x + ((size_t)b * T_ * N_ + n) * FN_;
    #pragma unroll
    for (int j = 0; j < 3; ++j) {
        float2 v = *(const float2*)(nb + (size_t)tt[j] * (N_ * FN_) + ff[j]);
        unsigned int pk = (unsigned int)f2bf(v.x) | ((unsigned int)f2bf(v.y) << 16);
        *(unsigned int*)(xr + 2 * (j * 64 + lane)) = pk;
    }

    // patch-mean part: cols [384,768)
    const int s = offsets[n];
    const int cnt = offsets[n + 1] - s;
    int p_l = 0;
    if (lane < cnt) p_l = edge_p[s + lane];
    float2 acc[3] = {{0.f,0.f},{0.f,0.f},{0.f,0.f}};
    const float* pb0 = patch_x + (size_t)b * (T_ * P_ * FP_);
    const int m = cnt < 64 ? cnt : 64;
    for (int q = 0; q < m; ++q) {
        const int p = __shfl(p_l, q);
        const float* pe = pb0 + p * FP_;
        #pragma unroll
        for (int j = 0; j < 3; ++j) {
            float2 v = *(const float2*)(pe + (size_t)tt[j] * (P_ * FP_) + ff[j]);
            acc[j].x += v.x; acc[j].y += v.y;
        }
    }
    for (int q = 64; q < cnt; ++q) {          // astronomically rare tail
        const int p = edge_p[s + q];
        const float* pe = pb0 + p * FP_;
        #pragma unroll
        for (int j = 0; j < 3; ++j) {
            float2 v = *(const float2*)(pe + (size_t)tt[j] * (P_ * FP_) + ff[j]);
            acc[j].x += v.x; acc[j].y += v.y;
        }
    }
    const float inv = cnt > 0 ? 1.0f / (float)cnt : 0.0f;
    #pragma unroll
    for (int j = 0; j < 3; ++j) {
        unsigned int pk = (unsigned int)f2bf(acc[j].x * inv) |
                          ((unsigned int)f2bf(acc[j].y * inv) << 16);
        *(unsigned int*)(xr + 384 + 2 * (j * 64 + lane)) = pk;
    }
}

// ---------------- GEMM1 fused: H=relu(X@W1+b1) (kept in LDS), then partial H@W2 per col-block ----------------
// grid: 7500 blocks (XCD-chunk-swizzled), 256 thr, 4 waves 2x2. part[ct][row][12] fp32 partials.
__global__ __launch_bounds__(256, 2) void k_gemm1(const unsigned short* __restrict__ X,
                                                  const unsigned short* __restrict__ W1t,
                                                  const float* __restrict__ b1,
                                                  const unsigned short* __restrict__ W2t,
                                                  float* __restrict__ part) {
    __shared__ __align__(16) unsigned short smem[16384];   // 32KB: As(8192) | Bs(8192); reused as Hs(16384)
    unsigned short* As = smem;
    unsigned short* Bs = smem + 8192;
    unsigned short* Hs = smem;                             // 128x128 bf16 after main loop

    // bijective XCD-chunked swizzle (nwg=7500, 8 XCDs): consecutive work ids land on one XCD
    const int id = blockIdx.x;
    const int q8 = 7500 >> 3, r8 = 7500 & 7;               // 937, 4
    const int xcd = id & 7, pos = id >> 3;
    const int nid = (xcd < r8) ? xcd * (q8 + 1) + pos
                               : r8 * (q8 + 1) + (xcd - r8) * q8 + pos;
    const int colt = nid % 6;
    const int rowt = nid / 6;
    const int col0 = colt * 128;
    const int row0 = rowt * 128;

    const int t = threadIdx.x;
    const int lane = t & 63;
    const int w = t >> 6;
    const int wr = w >> 1, wc = w & 1;
    const int l15 = lane & 15;
    const int lhi = lane >> 4;

    f32x4 acc[4][4] = {};

    for (int kt = 0; kt < 12; ++kt) {
        const int k0 = kt * 64;
        #pragma unroll
        for (int i = 0; i < 4; ++i) {
            const int f = i * 2048 + t * 8;
            GLDS16(X + (row0 + (f >> 6)) * IND + k0 + (f & 63), &As[f]);
        }
        #pragma unroll
        for (int i = 0; i < 4; ++i) {
            const int f = i * 2048 + t * 8;
            GLDS16(W1t + (col0 + (f >> 6)) * IND + k0 + (f & 63), &Bs[f]);
        }
        __syncthreads();
        #pragma unroll
        for (int kk = 0; kk < 2; ++kk) {
            const int ko = kk * 32 + lhi * 8;
            bf16x8 af[4], bfr[4];
            #pragma unroll
            for (int m = 0; m < 4; ++m)
                af[m] = *(const bf16x8*)&As[(wr * 64 + m * 16 + l15) * 64 + ko];
            #pragma unroll
            for (int n = 0; n < 4; ++n)
                bfr[n] = *(const bf16x8*)&Bs[(wc * 64 + n * 16 + l15) * 64 + ko];
            #pragma unroll
            for (int m = 0; m < 4; ++m)
                #pragma unroll
                for (int n = 0; n < 4; ++n)
                    acc[m][n] = __builtin_amdgcn_mfma_f32_16x16x32_bf16(af[m], bfr[n], acc[m][n], 0, 0, 0);
        }
        __syncthreads();
    }

    // epilogue A: bias + relu + bf16 into LDS Hs[128][128] (local row, local col)
    #pragma unroll
    for (int n = 0; n < 4; ++n) {
        const int lcol = wc * 64 + n * 16 + l15;
        const float bb = b1[col0 + lcol];
        #pragma unroll
        for (int m = 0; m < 4; ++m) {
            #pragma unroll
            for (int r = 0; r < 4; ++r) {
                const int lrow = wr * 64 + m * 16 + lhi * 4 + r;
                float v = acc[m][n][r] + bb;
                v = v > 0.f ? v : 0.f;
                Hs[lrow * 128 + lcol] = f2bf(v);
            }
        }
    }
    __syncthreads();

    // epilogue B: partial (128 rows x 12 out) = Hs @ W2t^T over k=128 local h-cols.
    // wave w owns local rows [w*32, w*32+32): 2 row-tiles x 4 MFMA (k=128).
    f32x4 p0 = {}, p1 = {};
    #pragma unroll
    for (int kk = 0; kk < 4; ++kk) {
        const int ko = kk * 32 + lhi * 8;
        bf16x8 bw = *(const bf16x8*)&W2t[l15 * IND + col0 + ko];
        bf16x8 a0 = *(const bf16x8*)&Hs[(w * 32 + l15) * 128 + ko];
        bf16x8 a1 = *(const bf16x8*)&Hs[(w * 32 + 16 + l15) * 128 + ko];
        p0 = __builtin_amdgcn_mfma_f32_16x16x32_bf16(a0, bw, p0, 0, 0, 0);
        p1 = __builtin_amdgcn_mfma_f32_16x16x32_bf16(a1, bw, p1, 0, 0, 0);
    }
    if (l15 < HO_) {
        float* pp = part + (size_t)colt * ((size_t)M_ * HO_);
        #pragma unroll
        for (int r = 0; r < 4; ++r) {
            const int g0 = row0 + w * 32 + lhi * 4 + r;
            pp[(size_t)g0 * HO_ + l15] = p0[r];
            pp[(size_t)(g0 + 16) * HO_ + l15] = p1[r];
        }
    }
}

// ---------------- reduce: out = b2 + sum_ct part[ct] ----------------
__global__ void k_reduce(const float* __restrict__ part, const float* __restrict__ b2,
                         float* __restrict__ out) {
    int i = blockIdx.x * 256 + threadIdx.x;
    if (i < M_ * HO_) {
        const int o = i % HO_;
        float s = b2[o];
        #pragma unroll
        for (int ct = 0; ct < 6; ++ct) s += part[(size_t)ct * ((size_t)M_ * HO_) + i];
        out[i] = s;
    }
}

extern "C" void kernel_launch(void* const* d_in, const int* in_sizes, int n_in,
                              void* d_out, int out_size, void* d_ws, size_t ws_size,
                              hipStream_t stream) {
    const float* patch_x = (const float*)d_in[0];
    const float* nodes_x = (const float*)d_in[1];
    const int*   sb      = (const int*)d_in[2];
    const int*   snm     = (const int*)d_in[3];
    const float* W1      = (const float*)d_in[4];
    const float* b1      = (const float*)d_in[5];
    const float* W2      = (const float*)d_in[6];
    const float* b2      = (const float*)d_in[7];
    float* out = (float*)d_out;

    char* ws = (char*)d_ws;
    size_t off = 0;
    auto alloc = [&](size_t bytes) -> void* {
        void* p = ws + off;
        off = (off + bytes + 255) & ~(size_t)255;
        return p;
    };
    int* counts  = (int*)alloc((size_t)N_ * 4);
    int* offsets = (int*)alloc((size_t)(N_ + 1) * 4);
    int* cursor  = (int*)alloc((size_t)N_ * 4);
    int* edge_p  = (int*)alloc((size_t)E_ * 4);
    unsigned short* W1t = (unsigned short*)alloc((size_t)IND * IND * 2);
    unsigned short* W2t = (unsigned short*)alloc((size_t)16 * IND * 2);
    unsigned short* X   = (unsigned short*)alloc((size_t)M_ * IND * 2);
    float* part         = (float*)alloc((size_t)6 * M_ * HO_ * 4);

    hipMemsetAsync(counts, 0, (size_t)N_ * 4, stream);
    k_count  <<<(E_ + 255) / 256, 256, 0, stream>>>(snm, counts);
    k_scan   <<<1, 1024, 0, stream>>>(counts, offsets, cursor);
    k_scatter<<<(E_ + 255) / 256, 256, 0, stream>>>(snm, sb, cursor, edge_p);
    k_wprep  <<<(IND * IND + 16 * IND) / 256, 256, 0, stream>>>(W1, W2, W1t, W2t);
    k_stage  <<<M_ / 4, 256, 0, stream>>>(patch_x, nodes_x, offsets, edge_p, X);
    k_gemm1  <<<7500, 256, 0, stream>>>(X, W1t, b1, W2t, part);
    k_reduce <<<(M_ * HO_ + 255) / 256, 256, 0, stream>>>(part, b2, out);
}

// Round 6
// 690.238 us; speedup vs baseline: 1.3983x; 1.0469x over previous
//
#include <hip/hip_runtime.h>

#define B_ 8
#define T_ 12
#define P_ 1000
#define N_ 20000
#define E_ 60000
#define FP_ 32
#define FN_ 32
#define HO_ 12
#define IND 768
#define M_ (B_*N_)   // 160000 rows

typedef __attribute__((ext_vector_type(8))) short bf16x8;
typedef __attribute__((ext_vector_type(4))) float f32x4;

__device__ __forceinline__ unsigned short f2bf(float x) {
    union { float f; unsigned int u; } v; v.f = x;
    unsigned int u = v.u;
    u += 0x7fffu + ((u >> 16) & 1u);   // RNE
    return (unsigned short)(u >> 16);
}

#define GLDS16(gp, lp) \
    __builtin_amdgcn_global_load_lds((const __attribute__((address_space(1))) void*)(gp), \
                                     (__attribute__((address_space(3))) void*)(lp), 16, 0, 0)

// ---------------- CSR build ----------------
__global__ void k_count(const int* __restrict__ mapper, int* __restrict__ counts) {
    int e = blockIdx.x * 256 + threadIdx.x;
    if (e < E_) atomicAdd(&counts[mapper[e]], 1);
}

__global__ __launch_bounds__(1024) void k_scan(const int* __restrict__ counts,
                                               int* __restrict__ offsets,
                                               int* __restrict__ cursor) {
    __shared__ int ps[1024];
    const int tid = threadIdx.x;
    const int CH = 20;                       // 1024*20 = 20480 >= N_
    const int base = tid * CH;
    int s = 0;
    for (int i = 0; i < CH; ++i) { int idx = base + i; if (idx < N_) s += counts[idx]; }
    ps[tid] = s;
    __syncthreads();
    for (int off = 1; off < 1024; off <<= 1) {
        int v = ps[tid];
        int a = (tid >= off) ? ps[tid - off] : 0;
        __syncthreads();
        ps[tid] = v + a;
        __syncthreads();
    }
    int run = (tid > 0) ? ps[tid - 1] : 0;   // exclusive base
    for (int i = 0; i < CH; ++i) {
        int idx = base + i;
        if (idx < N_) { offsets[idx] = run; cursor[idx] = run; run += counts[idx]; }
    }
    if (tid == 1023) offsets[N_] = ps[1023];
}

__global__ void k_scatter(const int* __restrict__ mapper, const int* __restrict__ batch,
                          int* __restrict__ cursor, int* __restrict__ edge_p) {
    int e = blockIdx.x * 256 + threadIdx.x;
    if (e < E_) {
        int pos = atomicAdd(&cursor[mapper[e]], 1);
        edge_p[pos] = batch[e];
    }
}

// ---------------- weight prep: W1t[h][d]=bf16(W1[d][h]); W2t[o<16][k]=bf16(W2[k][o]) ----------------
__global__ void k_wprep(const float* __restrict__ W1, const float* __restrict__ W2,
                        unsigned short* __restrict__ W1t, unsigned short* __restrict__ W2t) {
    int i = blockIdx.x * 256 + threadIdx.x;
    if (i < IND * IND) {
        int h = i / IND, d = i - h * IND;
        W1t[i] = f2bf(W1[d * IND + h]);
    } else {
        int j = i - IND * IND;
        if (j < 16 * IND) {
            int o = j / IND, k = j - o * IND;
            W2t[j] = (o < HO_) ? f2bf(W2[k * HO_ + o]) : (unsigned short)0;
        }
    }
}

// ---------------- stage mlp_in (bf16): row r=b*N+n, cols [0,384)=nodes_x^T, [384,768)=patch-mean ----------------
__global__ __launch_bounds__(256) void k_stage(const float* __restrict__ patch_x,
                                               const float* __restrict__ nodes_x,
                                               const int* __restrict__ offsets,
                                               const int* __restrict__ edge_p,
                                               unsigned short* __restrict__ X) {
    const int gw = (blockIdx.x * 256 + threadIdx.x) >> 6;   // one wave per row
    const int lane = threadIdx.x & 63;
    const int b = gw / N_;
    const int n = gw - b * N_;
    unsigned short* xr = X + (size_t)gw * IND;

    int tt[3], ff[3];
    #pragma unroll
    for (int j = 0; j < 3; ++j) {
        const int c = 2 * (j * 64 + lane);     // even col in [0,384)
        tt[j] = c >> 5; ff[j] = c & 31;        // pair (f, f+1) stays within one t
    }

    // nodes part: cols [0,384)
    const float* nb = nodes_x + ((size_t)b * T_ * N_ + n) * FN_;
    #pragma unroll
    for (int j = 0; j < 3; ++j) {
        float2 v = *(const float2*)(nb + (size_t)tt[j] * (N_ * FN_) + ff[j]);
        unsigned int pk = (unsigned int)f2bf(v.x) | ((unsigned int)f2bf(v.y) << 16);
        *(unsigned int*)(xr + 2 * (j * 64 + lane)) = pk;
    }

    // patch-mean part: cols [384,768)
    const int s = offsets[n];
    const int cnt = offsets[n + 1] - s;
    int p_l = 0;
    if (lane < cnt) p_l = edge_p[s + lane];
    float2 acc[3] = {{0.f,0.f},{0.f,0.f},{0.f,0.f}};
    const float* pb0 = patch_x + (size_t)b * (T_ * P_ * FP_);
    const int m = cnt < 64 ? cnt : 64;
    for (int q = 0; q < m; ++q) {
        const int p = __shfl(p_l, q);
        const float* pe = pb0 + p * FP_;
        #pragma unroll
        for (int j = 0; j < 3; ++j) {
            float2 v = *(const float2*)(pe + (size_t)tt[j] * (P_ * FP_) + ff[j]);
            acc[j].x += v.x; acc[j].y += v.y;
        }
    }
    for (int q = 64; q < cnt; ++q) {          // astronomically rare tail
        const int p = edge_p[s + q];
        const float* pe = pb0 + p * FP_;
        #pragma unroll
        for (int j = 0; j < 3; ++j) {
            float2 v = *(const float2*)(pe + (size_t)tt[j] * (P_ * FP_) + ff[j]);
            acc[j].x += v.x; acc[j].y += v.y;
        }
    }
    const float inv = cnt > 0 ? 1.0f / (float)cnt : 0.0f;
    #pragma unroll
    for (int j = 0; j < 3; ++j) {
        unsigned int pk = (unsigned int)f2bf(acc[j].x * inv) |
                          ((unsigned int)f2bf(acc[j].y * inv) << 16);
        *(unsigned int*)(xr + 384 + 2 * (j * 64 + lane)) = pk;
    }
}

// ======================= GEMM1: 256x256 tile, BK=64, 8-phase schedule =======================
// 8 waves (2M x 4N), 512 thr, LDS 128KB dbuf, XOR chunk-swizzle, counted vmcnt, setprio.
// Fused: H = relu(X@W1+b1) -> LDS; partial H@W2 -> part[colt] (colt in 0..2).

#define BARRIER() __builtin_amdgcn_s_barrier()
#define LGKM0()  { asm volatile("s_waitcnt lgkmcnt(0)" ::: "memory"); __builtin_amdgcn_sched_barrier(0); }
#define VMC(n)   { asm volatile("s_waitcnt vmcnt(" #n ")" ::: "memory"); }

__global__ __launch_bounds__(512, 1) void k_gemm1(const unsigned short* __restrict__ X,
                                                  const unsigned short* __restrict__ W1t,
                                                  const float* __restrict__ b1,
                                                  const unsigned short* __restrict__ W2t,
                                                  float* __restrict__ part) {
    __shared__ __align__(16) unsigned short lds[65536];   // 128 KiB: buf[2] x (A 16384 | B 16384) shorts

    // bijective XCD-chunked swizzle: nwg=1875, q=234, r=3
    const int id = blockIdx.x;
    const int xcd = id & 7, pos = id >> 3;
    const int nid = (xcd < 3) ? xcd * 235 + pos : 3 * 235 + (xcd - 3) * 234 + pos;
    const int colt = nid % 3;            // colt fastest: 3 consecutive blocks share A-panel in L2
    const int rowt = nid / 3;
    const int row0 = rowt * 256;
    const int col0 = colt * 256;

    const int t = threadIdx.x;
    const int lane = t & 63;
    const int w = t >> 6;                // 8 waves
    const int wm = w >> 2;               // 0..1  (M half)
    const int wn = w & 3;                // 0..3  (N quarter)
    const int l15 = lane & 15;
    const int lhi = lane >> 4;

    // staging address precompute (involution: source chunk = stored chunk ^ (row&7))
    const int sr = t >> 3;               // row within half-tile half (0..63)
    const int sc = (t & 7) ^ (sr & 7);   // source chunk index
    // frag read precompute
    const int arow = wm * 128 + l15;
    const int brow = wn * 64 + l15;
    const int axor = l15 & 7;

    // STAGE(k, sec, hf): stage one half-tile (128 rows x 64 cols bf16) of K-tile k.
    // sec: 0 = A (from X rows row0+), 1 = B (from W1t rows col0+). 2 loads/thread.
#define STAGE(k, sec, hf) { \
        const unsigned short* _s = (sec) ? (W1t + (size_t)(col0 + (hf)*128 + sr) * IND + (k)*64 + sc*8) \
                                         : (X   + (size_t)(row0 + (hf)*128 + sr) * IND + (k)*64 + sc*8); \
        unsigned short* _d = &lds[(((k)&1) << 15) + ((sec) << 14) + ((hf) << 13) + t*8]; \
        GLDS16(_s, _d); \
        GLDS16(_s + (size_t)64*IND, _d + 4096); }

#define LDA4(buf, mlo) \
        _Pragma("unroll") for (int m_ = 0; m_ < 4; ++m_) \
        _Pragma("unroll") for (int ks_ = 0; ks_ < 2; ++ks_) \
            a_reg[(mlo)+m_][ks_] = *(const bf16x8*)&lds[((buf) << 15) + (arow + ((mlo)+m_)*16)*64 + (((ks_*4+lhi) ^ axor) << 3)];

#define LDB2(buf, nlo) \
        _Pragma("unroll") for (int n_ = 0; n_ < 2; ++n_) \
        _Pragma("unroll") for (int ks_ = 0; ks_ < 2; ++ks_) \
            b_reg[(nlo)+n_][ks_] = *(const bf16x8*)&lds[((buf) << 15) + 16384 + (brow + ((nlo)+n_)*16)*64 + (((ks_*4+lhi) ^ axor) << 3)];

#define MFMA_Q(mlo, nlo) \
        __builtin_amdgcn_s_setprio(1); \
        _Pragma("unroll") for (int m_ = 0; m_ < 4; ++m_) \
        _Pragma("unroll") for (int n_ = 0; n_ < 2; ++n_) \
        _Pragma("unroll") for (int ks_ = 0; ks_ < 2; ++ks_) \
            acc[(mlo)+m_][(nlo)+n_] = __builtin_amdgcn_mfma_f32_16x16x32_bf16( \
                a_reg[(mlo)+m_][ks_], b_reg[(nlo)+n_][ks_], acc[(mlo)+m_][(nlo)+n_], 0, 0, 0); \
        __builtin_amdgcn_s_setprio(0);

    f32x4 acc[8][4] = {};
    bf16x8 a_reg[8][2], b_reg[4][2];

    // prologue: kt0 fully -> buf0; kt1 A-halves -> buf1 (12 loads/thread issued)
    STAGE(0, 0, 0); STAGE(0, 0, 1); STAGE(0, 1, 0); STAGE(0, 1, 1);
    STAGE(1, 0, 0); STAGE(1, 0, 1);
    VMC(4);                    // kt0's 8 loads done; kt1.A (4) in flight
    BARRIER();

    for (int it = 0; it < 6; ++it) {
        const int a = 2 * it, b = 2 * it + 1;
        const bool more = (it < 5);
        // ---- K-tile a (buf0) ----
        // P0
        LDA4(0, 0); LDB2(0, 0);
        STAGE(b, 1, 0);
        BARRIER(); LGKM0();
        MFMA_Q(0, 0);
        BARRIER();
        // P1
        LDA4(0, 4);
        STAGE(b, 1, 1);
        BARRIER(); LGKM0();
        MFMA_Q(4, 0);
        BARRIER();
        // P2
        LDB2(0, 2);
        if (more) STAGE(a + 2, 0, 0);
        BARRIER(); LGKM0();
        MFMA_Q(0, 2);
        BARRIER();
        // P3 (no ds reads; gate next buffer)
        if (more) STAGE(a + 2, 0, 1);
        BARRIER();
        MFMA_Q(4, 2);
        if (more) { VMC(4); } else { VMC(0); }   // K-tile b fully landed
        BARRIER();
        // ---- K-tile b (buf1) ----
        // P4
        LDA4(1, 0); LDB2(1, 0);
        if (more) STAGE(a + 2, 1, 0);
        BARRIER(); LGKM0();
        MFMA_Q(0, 0);
        BARRIER();
        // P5
        LDA4(1, 4);
        if (more) STAGE(a + 2, 1, 1);
        BARRIER(); LGKM0();
        MFMA_Q(4, 0);
        BARRIER();
        // P6
        LDB2(1, 2);
        if (more) STAGE(b + 2, 0, 0);
        BARRIER(); LGKM0();
        MFMA_Q(0, 2);
        BARRIER();
        // P7
        if (more) STAGE(b + 2, 0, 1);
        BARRIER();
        MFMA_Q(4, 2);
        if (more) { VMC(4); } else { VMC(0); }   // K-tile a+2 fully landed
        BARRIER();
    }

    // ---- epilogue A: bias + relu -> bf16 H tile in LDS (256x256, XOR-swizzled chunks) ----
    #pragma unroll
    for (int n = 0; n < 4; ++n) {
        const int col = wn * 64 + n * 16 + l15;
        const float bb = b1[col0 + col];
        const int c8 = col >> 3, c7 = col & 7;
        #pragma unroll
        for (int m = 0; m < 8; ++m) {
            #pragma unroll
            for (int r = 0; r < 4; ++r) {
                const int row = wm * 128 + m * 16 + lhi * 4 + r;
                float v = acc[m][n][r] + bb;
                v = v > 0.f ? v : 0.f;
                lds[row * 256 + ((c8 ^ (row & 7)) << 3) + c7] = f2bf(v);
            }
        }
    }
    asm volatile("s_waitcnt lgkmcnt(0)" ::: "memory");
    BARRIER();

    // ---- epilogue B: partial (256 rows x 12) = H @ W2 over local k=256 ----
    f32x4 p0 = {}, p1 = {};
    const int er0 = w * 32 + l15;
    const int er1 = er0 + 16;
    const int ex = er0 & 7;              // == er1 & 7
    #pragma unroll
    for (int kk = 0; kk < 8; ++kk) {
        const int kc = kk * 4 + lhi;     // chunk 0..31
        bf16x8 bw = *(const bf16x8*)&W2t[l15 * IND + col0 + kk * 32 + lhi * 8];
        bf16x8 a0 = *(const bf16x8*)&lds[er0 * 256 + ((kc ^ ex) << 3)];
        bf16x8 a1 = *(const bf16x8*)&lds[er1 * 256 + ((kc ^ ex) << 3)];
        p0 = __builtin_amdgcn_mfma_f32_16x16x32_bf16(a0, bw, p0, 0, 0, 0);
        p1 = __builtin_amdgcn_mfma_f32_16x16x32_bf16(a1, bw, p1, 0, 0, 0);
    }
    if (l15 < HO_) {
        float* pp = part + (size_t)colt * ((size_t)M_ * HO_);
        #pragma unroll
        for (int r = 0; r < 4; ++r) {
            const int g0 = row0 + w * 32 + lhi * 4 + r;
            pp[(size_t)g0 * HO_ + l15] = p0[r];
            pp[(size_t)(g0 + 16) * HO_ + l15] = p1[r];
        }
    }
#undef STAGE
#undef LDA4
#undef LDB2
#undef MFMA_Q
}

// ---------------- reduce: out = b2 + sum_ct part[ct] ----------------
__global__ void k_reduce(const float* __restrict__ part, const float* __restrict__ b2,
                         float* __restrict__ out) {
    int i = blockIdx.x * 256 + threadIdx.x;
    if (i < M_ * HO_) {
        const int o = i % HO_;
        float s = b2[o];
        #pragma unroll
        for (int ct = 0; ct < 3; ++ct) s += part[(size_t)ct * ((size_t)M_ * HO_) + i];
        out[i] = s;
    }
}

extern "C" void kernel_launch(void* const* d_in, const int* in_sizes, int n_in,
                              void* d_out, int out_size, void* d_ws, size_t ws_size,
                              hipStream_t stream) {
    const float* patch_x = (const float*)d_in[0];
    const float* nodes_x = (const float*)d_in[1];
    const int*   sb      = (const int*)d_in[2];
    const int*   snm     = (const int*)d_in[3];
    const float* W1      = (const float*)d_in[4];
    const float* b1      = (const float*)d_in[5];
    const float* W2      = (const float*)d_in[6];
    const float* b2      = (const float*)d_in[7];
    float* out = (float*)d_out;

    char* ws = (char*)d_ws;
    size_t off = 0;
    auto alloc = [&](size_t bytes) -> void* {
        void* p = ws + off;
        off = (off + bytes + 255) & ~(size_t)255;
        return p;
    };
    int* counts  = (int*)alloc((size_t)N_ * 4);
    int* offsets = (int*)alloc((size_t)(N_ + 1) * 4);
    int* cursor  = (int*)alloc((size_t)N_ * 4);
    int* edge_p  = (int*)alloc((size_t)E_ * 4);
    unsigned short* W1t = (unsigned short*)alloc((size_t)IND * IND * 2);
    unsigned short* W2t = (unsigned short*)alloc((size_t)16 * IND * 2);
    unsigned short* X   = (unsigned short*)alloc((size_t)M_ * IND * 2);
    float* part         = (float*)alloc((size_t)3 * M_ * HO_ * 4);

    hipMemsetAsync(counts, 0, (size_t)N_ * 4, stream);
    k_count  <<<(E_ + 255) / 256, 256, 0, stream>>>(snm, counts);
    k_scan   <<<1, 1024, 0, stream>>>(counts, offsets, cursor);
    k_scatter<<<(E_ + 255) / 256, 256, 0, stream>>>(snm, sb, cursor, edge_p);
    k_wprep  <<<(IND * IND + 16 * IND) / 256, 256, 0, stream>>>(W1, W2, W1t, W2t);
    k_stage  <<<M_ / 4, 256, 0, stream>>>(patch_x, nodes_x, offsets, edge_p, X);
    k_gemm1  <<<1875, 512, 0, stream>>>(X, W1t, b1, W2t, part);
    k_reduce <<<(M_ * HO_ + 255) / 256, 256, 0, stream>>>(part, b2, out);
}